// Round 5
// baseline (421.676 us; speedup 1.0000x reference)
//
#include <hip/hip_runtime.h>

#define B_  2
#define N_  100000
#define NE_ 800000
#define F_  2
#define D_  128
#define TD_ 11
#define CD_ 32
#define SD_ 10

typedef short s16x8 __attribute__((ext_vector_type(8)));
typedef float f32x4 __attribute__((ext_vector_type(4)));

static __device__ __forceinline__ unsigned short f2bf(float f) {
    unsigned u = __builtin_bit_cast(unsigned, f);
    u += 0x7FFFu + ((u >> 16) & 1u);   // RNE
    return (unsigned short)(u >> 16);
}
static __device__ __forceinline__ float silu_f(float x) { return x / (1.0f + __expf(-x)); }

// ---------------------------------------------------------------------------
// Kernel A: FiLM gamma/beta (tiny, f32). grid=(B), block=(128). -> gb in ws.
// Also writes a host-computed sentinel into V[0] if the input mapping looked
// wrong (sentinel==0 -> no write).
// ---------------------------------------------------------------------------
__global__ void film_kernel(
    const float* __restrict__ time_i, const float* __restrict__ cond,
    const float* __restrict__ spat,
    const float* tw1, const float* tb1, const float* tw2, const float* tb2,
    const float* cw1, const float* cb1, const float* cw2, const float* cb2,
    const float* sw1, const float* sb1, const float* sw2, const float* sb2,
    const float* fw1, const float* fb1, const float* fw2, const float* fb2,
    float* __restrict__ gb, float* __restrict__ V, float sentinel)
{
    const int b = blockIdx.x, d = threadIdx.x;
    __shared__ float h[3 * D_];
    __shared__ float hid[D_];

    if (b == 0 && d == 0 && sentinel != 0.f) V[0] = sentinel;

    const float* xs[3]  = { cond + b * CD_, time_i + b * TD_, spat + b * SD_ };
    const int    Ks[3]  = { CD_, TD_, SD_ };
    const float* w1s[3] = { cw1, tw1, sw1 };
    const float* b1s[3] = { cb1, tb1, sb1 };
    const float* w2s[3] = { cw2, tw2, sw2 };
    const float* b2s[3] = { cb2, tb2, sb2 };

    for (int m = 0; m < 3; ++m) {
        float a = b1s[m][d];
        for (int k = 0; k < Ks[m]; ++k) a += xs[m][k] * w1s[m][k * D_ + d];
        __syncthreads();
        hid[d] = silu_f(a);
        __syncthreads();
        float o = b2s[m][d];
        for (int k = 0; k < D_; ++k) o += hid[k] * w2s[m][k * D_ + d];
        h[m * D_ + d] = o;
    }
    __syncthreads();
    float a = fb1[d];
    for (int k = 0; k < 3 * D_; ++k) a += h[k] * fw1[k * D_ + d];
    __syncthreads();
    hid[d] = silu_f(a);
    __syncthreads();
    float g = fb2[d], be = fb2[D_ + d];
    for (int k = 0; k < D_; ++k) {
        float hv = hid[k];
        g  += hv * fw2[k * 2 * D_ + d];
        be += hv * fw2[k * 2 * D_ + D_ + d];
    }
    gb[(b * 2 + 0) * D_ + d] = g;
    gb[(b * 2 + 1) * D_ + d] = be;
}

// ---------------------------------------------------------------------------
// Kernel B: per-node per-field MLP + FiLM. 128 nodes/block, 256 threads (4 wv).
// Layer1 f32 in registers (A-frag layout); layer2 bf16 MFMA; f32 direct store.
// ---------------------------------------------------------------------------
__global__ __launch_bounds__(256, 2) void node_kernel(
    const float* __restrict__ pos,    // [B][N][3]
    const float* __restrict__ state,  // [B][N][F]
    const float* __restrict__ fw1,    // [F][4][D]
    const float* __restrict__ fb1,    // [F][D]
    const float* __restrict__ fw2,    // [F][D][D]
    const float* __restrict__ fb2,    // [F][D]
    const float* __restrict__ gb,     // [B][2][D]
    float* __restrict__ V)            // [B][N][F][D] f32
{
    const int t  = threadIdx.x;
    const int lane = t & 63, wv = t >> 6;
    const int kg = lane >> 4, lr = lane & 15;
    const int f = blockIdx.y, b = blockIdx.z;
    const int n0 = blockIdx.x * 128;

    __shared__ __align__(16) unsigned short lw2t[128 * 136];  // w2^T bf16
    __shared__ __align__(16) float lw1f[128 * 8];             // [col]{w0..w3,b1}

    {   // stage w2^T (f32 -> bf16): lw2t[o*136+e] = bf16(w2[f][e][o])
        const float* w2p = fw2 + f * D_ * D_;
        const int r = t >> 1, c0 = (t & 1) * 64;
        #pragma unroll
        for (int j = 0; j < 64; j += 4) {
            f32x4 v = *(const f32x4*)(w2p + r * D_ + c0 + j);
            #pragma unroll
            for (int q = 0; q < 4; ++q)
                lw2t[(c0 + j + q) * 136 + r] = f2bf(v[q]);
        }
    }
    if (t < 128) {
        const float* w1p = fw1 + f * 4 * D_;
        #pragma unroll
        for (int k = 0; k < 4; ++k) lw1f[t * 8 + k] = w1p[k * D_ + t];
        lw1f[t * 8 + 4] = fb1[f * D_ + t];
    }

    float xa[4], xb[4];
    {
        int na = n0 + wv * 32 + lr;      if (na >= N_) na = N_ - 1;
        int nb = n0 + wv * 32 + lr + 16; if (nb >= N_) nb = N_ - 1;
        long pa = ((long)b * N_ + na) * 3, pb = ((long)b * N_ + nb) * 3;
        xa[0] = pos[pa]; xa[1] = pos[pa + 1]; xa[2] = pos[pa + 2];
        xb[0] = pos[pb]; xb[1] = pos[pb + 1]; xb[2] = pos[pb + 2];
        xa[3] = state[((long)b * N_ + na) * F_ + f];
        xb[3] = state[((long)b * N_ + nb) * F_ + f];
    }
    __syncthreads();

    f32x4 acc[2][8];
    #pragma unroll
    for (int mt = 0; mt < 2; ++mt)
        #pragma unroll
        for (int nt = 0; nt < 8; ++nt) acc[mt][nt] = (f32x4){0.f, 0.f, 0.f, 0.f};

    #pragma unroll
    for (int kb = 0; kb < 4; ++kb) {
        const int e0 = kb * 32 + kg * 8;
        s16x8 ua, ub;
        #pragma unroll
        for (int i = 0; i < 8; ++i) {
            const float* wp = lw1f + (e0 + i) * 8;
            float w0 = wp[0], w1 = wp[1], w2 = wp[2], w3 = wp[3], bb = wp[4];
            ua[i] = (short)f2bf(silu_f(xa[0]*w0 + xa[1]*w1 + xa[2]*w2 + xa[3]*w3 + bb));
            ub[i] = (short)f2bf(silu_f(xb[0]*w0 + xb[1]*w1 + xb[2]*w2 + xb[3]*w3 + bb));
        }
        #pragma unroll
        for (int nt = 0; nt < 8; ++nt) {
            s16x8 bfr = *(const s16x8*)(lw2t + (nt * 16 + lr) * 136 + e0);
            acc[0][nt] = __builtin_amdgcn_mfma_f32_16x16x32_bf16(ua, bfr, acc[0][nt], 0, 0, 0);
            acc[1][nt] = __builtin_amdgcn_mfma_f32_16x16x32_bf16(ub, bfr, acc[1][nt], 0, 0, 0);
        }
    }

    // Epilogue: FiLM + direct f32 stores.  col = nt*16+lr, row m = wv*32+mt*16+kg*4+r
    const float* gamma = gb + b * 2 * D_;
    const float* beta  = gamma + D_;
    #pragma unroll
    for (int nt = 0; nt < 8; ++nt) {
        const int col = nt * 16 + lr;
        const float g = gamma[col], be = beta[col];
        const float bs = fb2[f * D_ + col];
        #pragma unroll
        for (int mt = 0; mt < 2; ++mt) {
            const int mbase = wv * 32 + mt * 16 + kg * 4;
            #pragma unroll
            for (int r = 0; r < 4; ++r) {
                const int n = n0 + mbase + r;
                if (n < N_)
                    V[(((long)b * N_ + n) * F_ + f) * D_ + col] = (acc[mt][nt][r] + bs) * g + be;
            }
        }
    }
}

// ---------------------------------------------------------------------------
// Kernel C: edge MLP. 128 edges/block, 256 threads. Self-probes edge dtype.
// feat=[d,-d,norm] folded to 4 inputs. f32 direct store.
// ---------------------------------------------------------------------------
__global__ __launch_bounds__(256, 2) void edge_kernel(
    const float* __restrict__ pos,    // [B][N][3]
    const int*   __restrict__ edges,  // [B][NE][2] int32 OR int64 (probed)
    const float* __restrict__ ew1,    // [7][D]
    const float* __restrict__ eb1,    // [D]
    const float* __restrict__ ew2,    // [D][D]
    const float* __restrict__ eb2,    // [D]
    float* __restrict__ E)            // [B][NE][D] f32
{
    const int t  = threadIdx.x;
    const int lane = t & 63, wv = t >> 6;
    const int kg = lane >> 4, lr = lane & 15;
    const int b = blockIdx.y;
    const int e0blk = blockIdx.x * 128;

    __shared__ __align__(16) unsigned short lw2t[128 * 136];
    __shared__ __align__(16) float lw1f[128 * 8];
    __shared__ int sx64;

    if (t == 0) {   // int64 edges => every odd int32 word of the first 64 is 0
        int nz = 0;
        for (int j = 0; j < 64; ++j) nz |= edges[2 * j + 1];
        sx64 = (nz == 0) ? 1 : 0;
    }

    {
        const int r = t >> 1, c0 = (t & 1) * 64;
        #pragma unroll
        for (int j = 0; j < 64; j += 4) {
            f32x4 v = *(const f32x4*)(ew2 + r * D_ + c0 + j);
            #pragma unroll
            for (int q = 0; q < 4; ++q)
                lw2t[(c0 + j + q) * 136 + r] = f2bf(v[q]);
        }
    }
    if (t < 128) {
        #pragma unroll
        for (int k = 0; k < 7; ++k) lw1f[t * 8 + k] = ew1[k * D_ + t];
        lw1f[t * 8 + 7] = eb1[t];
    }
    __syncthreads();   // lw2t, lw1f, sx64 ready

    float xa[4], xb[4];
    {
        const bool x64 = (sx64 != 0);
        const long ea = (long)b * NE_ + e0blk + wv * 32 + lr;
        const long eb = ea + 16;
        int sa, ra, sb, rb;
        if (x64) {
            sa = edges[ea * 4]; ra = edges[ea * 4 + 2];
            sb = edges[eb * 4]; rb = edges[eb * 4 + 2];
        } else {
            int2 va = *(const int2*)(edges + ea * 2); sa = va.x; ra = va.y;
            int2 vb = *(const int2*)(edges + eb * 2); sb = vb.x; rb = vb.y;
        }
        const float* pp = pos + (long)b * N_ * 3;
        {
            long so = (long)sa * 3, ro = (long)ra * 3;
            xa[0] = pp[ro]     - pp[so];
            xa[1] = pp[ro + 1] - pp[so + 1];
            xa[2] = pp[ro + 2] - pp[so + 2];
            xa[3] = sqrtf(xa[0]*xa[0] + xa[1]*xa[1] + xa[2]*xa[2] + 1e-8f);
        }
        {
            long so = (long)sb * 3, ro = (long)rb * 3;
            xb[0] = pp[ro]     - pp[so];
            xb[1] = pp[ro + 1] - pp[so + 1];
            xb[2] = pp[ro + 2] - pp[so + 2];
            xb[3] = sqrtf(xb[0]*xb[0] + xb[1]*xb[1] + xb[2]*xb[2] + 1e-8f);
        }
    }

    f32x4 acc[2][8];
    #pragma unroll
    for (int mt = 0; mt < 2; ++mt)
        #pragma unroll
        for (int nt = 0; nt < 8; ++nt) acc[mt][nt] = (f32x4){0.f, 0.f, 0.f, 0.f};

    #pragma unroll
    for (int kb = 0; kb < 4; ++kb) {
        const int e0 = kb * 32 + kg * 8;
        s16x8 ua, ub;
        #pragma unroll
        for (int i = 0; i < 8; ++i) {
            const float* wp = lw1f + (e0 + i) * 8;
            float w0 = wp[0] - wp[3];
            float w1 = wp[1] - wp[4];
            float w2 = wp[2] - wp[5];
            float w6 = wp[6];
            float bb = wp[7];
            ua[i] = (short)f2bf(silu_f(xa[0]*w0 + xa[1]*w1 + xa[2]*w2 + xa[3]*w6 + bb));
            ub[i] = (short)f2bf(silu_f(xb[0]*w0 + xb[1]*w1 + xb[2]*w2 + xb[3]*w6 + bb));
        }
        #pragma unroll
        for (int nt = 0; nt < 8; ++nt) {
            s16x8 bfr = *(const s16x8*)(lw2t + (nt * 16 + lr) * 136 + e0);
            acc[0][nt] = __builtin_amdgcn_mfma_f32_16x16x32_bf16(ua, bfr, acc[0][nt], 0, 0, 0);
            acc[1][nt] = __builtin_amdgcn_mfma_f32_16x16x32_bf16(ub, bfr, acc[1][nt], 0, 0, 0);
        }
    }

    #pragma unroll
    for (int nt = 0; nt < 8; ++nt) {
        const int col = nt * 16 + lr;
        const float bs = eb2[col];
        #pragma unroll
        for (int mt = 0; mt < 2; ++mt) {
            const int mbase = wv * 32 + mt * 16 + kg * 4;
            #pragma unroll
            for (int r = 0; r < 4; ++r) {
                const long e = (long)b * NE_ + e0blk + mbase + r;
                E[e * D_ + col] = acc[mt][nt][r] + bs;
            }
        }
    }
}

// ---------------------------------------------------------------------------
extern "C" void kernel_launch(void* const* d_in, const int* in_sizes, int n_in,
                              void* d_out, int out_size, void* d_ws, size_t ws_size,
                              hipStream_t stream)
{
    (void)out_size; (void)ws_size;

    static const int kDictSizes[30] = {
        600000, 400000, 22, 64, 20, 3200000,
        1024, 256, 32768, 256,
        1408, 128, 16384, 128,
        4096, 128, 16384, 128,
        1280, 128, 16384, 128,
        49152, 128, 32768, 256,
        896, 128, 16384, 128 };

    float sentinel = 0.f;                 // diagnostic channel (only on anomaly)
    if (n_in != 30) sentinel = 1.0e6f;
    else {
        for (int i = 0; i < 30; ++i)
            if (in_sizes[i] != kDictSizes[i] &&
                !(i == 5 && in_sizes[i] == 2 * kDictSizes[i])) { sentinel = 2.0e6f; break; }
    }

    const float* node_pos  = (const float*)d_in[0];
    const float* state_in  = (const float*)d_in[1];
    const float* time_i    = (const float*)d_in[2];
    const float* conditions= (const float*)d_in[3];
    const float* spatial   = (const float*)d_in[4];
    const int*   edges     = (const int*)d_in[5];
    const float* fields_w1 = (const float*)d_in[6];
    const float* fields_b1 = (const float*)d_in[7];
    const float* fields_w2 = (const float*)d_in[8];
    const float* fields_b2 = (const float*)d_in[9];
    const float* tw1 = (const float*)d_in[10];
    const float* tb1 = (const float*)d_in[11];
    const float* tw2 = (const float*)d_in[12];
    const float* tb2 = (const float*)d_in[13];
    const float* cw1 = (const float*)d_in[14];
    const float* cb1 = (const float*)d_in[15];
    const float* cw2 = (const float*)d_in[16];
    const float* cb2 = (const float*)d_in[17];
    const float* sw1 = (const float*)d_in[18];
    const float* sb1 = (const float*)d_in[19];
    const float* sw2 = (const float*)d_in[20];
    const float* sb2 = (const float*)d_in[21];
    const float* fu_w1 = (const float*)d_in[22];
    const float* fu_b1 = (const float*)d_in[23];
    const float* fu_w2 = (const float*)d_in[24];
    const float* fu_b2 = (const float*)d_in[25];
    const float* fe_w1 = (const float*)d_in[26];
    const float* fe_b1 = (const float*)d_in[27];
    const float* fe_w2 = (const float*)d_in[28];
    const float* fe_b2 = (const float*)d_in[29];

    float* gb = (float*)d_ws;                 // [B][2][D] f32
    float* V  = (float*)d_out;                // [B][N][F][D] f32
    float* E  = V + (long)B_ * N_ * F_ * D_;  // [B][NE][D] f32

    film_kernel<<<dim3(B_), dim3(128), 0, stream>>>(
        time_i, conditions, spatial,
        tw1, tb1, tw2, tb2, cw1, cb1, cw2, cb2, sw1, sb1, sw2, sb2,
        fu_w1, fu_b1, fu_w2, fu_b2, gb, V, sentinel);

    node_kernel<<<dim3((N_ + 127) / 128, F_, B_), dim3(256), 0, stream>>>(
        node_pos, state_in, fields_w1, fields_b1, fields_w2, fields_b2, gb, V);

    edge_kernel<<<dim3(NE_ / 128, B_), dim3(256), 0, stream>>>(
        node_pos, edges, fe_w1, fe_b1, fe_w2, fe_b2, E);
}

// Round 6
// 332.709 us; speedup vs baseline: 1.2674x; 1.2674x over previous
//
#include <hip/hip_runtime.h>

#define B_  2
#define N_  100000
#define NE_ 800000
#define F_  2
#define D_  128
#define TD_ 11
#define CD_ 32
#define SD_ 10

#define NODE_BX   782                      // ceil(N/128)
#define NODE_NB   (NODE_BX * F_ * B_)      // 3128
#define EDGE_BX   6250                     // NE/128
#define EDGE_NB   (EDGE_BX * B_)           // 12500
#define GROUPS    3125                     // interleave groups of 5 (1 node + 4 edge)
#define TOTAL_NB  (NODE_NB + EDGE_NB)      // 15628

typedef short s16x8 __attribute__((ext_vector_type(8)));
typedef float f32x4 __attribute__((ext_vector_type(4)));

static __device__ __forceinline__ unsigned short f2bf(float f) {
    unsigned u = __builtin_bit_cast(unsigned, f);
    u += 0x7FFFu + ((u >> 16) & 1u);   // RNE
    return (unsigned short)(u >> 16);
}
static __device__ __forceinline__ float silu_f(float x) { return x / (1.0f + __expf(-x)); }

// ---------------------------------------------------------------------------
// Kernel A: FiLM gamma/beta (tiny, f32). grid=(B), block=(128). -> gb in ws.
// ---------------------------------------------------------------------------
__global__ void film_kernel(
    const float* __restrict__ time_i, const float* __restrict__ cond,
    const float* __restrict__ spat,
    const float* tw1, const float* tb1, const float* tw2, const float* tb2,
    const float* cw1, const float* cb1, const float* cw2, const float* cb2,
    const float* sw1, const float* sb1, const float* sw2, const float* sb2,
    const float* fw1, const float* fb1, const float* fw2, const float* fb2,
    float* __restrict__ gb)
{
    const int b = blockIdx.x, d = threadIdx.x;
    __shared__ float h[3 * D_];
    __shared__ float hid[D_];

    const float* xs[3]  = { cond + b * CD_, time_i + b * TD_, spat + b * SD_ };
    const int    Ks[3]  = { CD_, TD_, SD_ };
    const float* w1s[3] = { cw1, tw1, sw1 };
    const float* b1s[3] = { cb1, tb1, sb1 };
    const float* w2s[3] = { cw2, tw2, sw2 };
    const float* b2s[3] = { cb2, tb2, sb2 };

    for (int m = 0; m < 3; ++m) {
        float a = b1s[m][d];
        for (int k = 0; k < Ks[m]; ++k) a += xs[m][k] * w1s[m][k * D_ + d];
        __syncthreads();
        hid[d] = silu_f(a);
        __syncthreads();
        float o = b2s[m][d];
        for (int k = 0; k < D_; ++k) o += hid[k] * w2s[m][k * D_ + d];
        h[m * D_ + d] = o;
    }
    __syncthreads();
    float a = fb1[d];
    for (int k = 0; k < 3 * D_; ++k) a += h[k] * fw1[k * D_ + d];
    __syncthreads();
    hid[d] = silu_f(a);
    __syncthreads();
    float g = fb2[d], be = fb2[D_ + d];
    for (int k = 0; k < D_; ++k) {
        float hv = hid[k];
        g  += hv * fw2[k * 2 * D_ + d];
        be += hv * fw2[k * 2 * D_ + D_ + d];
    }
    gb[(b * 2 + 0) * D_ + d] = g;
    gb[(b * 2 + 1) * D_ + d] = be;
}

// ---------------------------------------------------------------------------
// Node role: 128 nodes, 256 threads. Layer1 f32 regs (A-frag layout);
// layer2 bf16 MFMA; FiLM epilogue; nontemporal f32 stores.
// ---------------------------------------------------------------------------
static __device__ __forceinline__ void node_body(
    int sub, int t, unsigned short* lw2t, float* lw1f,
    const float* __restrict__ pos, const float* __restrict__ state,
    const float* __restrict__ fw1, const float* __restrict__ fb1,
    const float* __restrict__ fw2, const float* __restrict__ fb2,
    const float* __restrict__ gb, float* __restrict__ V)
{
    const int lane = t & 63, wv = t >> 6;
    const int kg = lane >> 4, lr = lane & 15;
    const int n0 = (sub % NODE_BX) * 128;
    const int f  = (sub / NODE_BX) & 1;
    const int b  = sub / (NODE_BX * F_);

    {   // stage w2^T (f32 -> bf16): lw2t[o*136+e] = bf16(w2[f][e][o])
        const float* w2p = fw2 + f * D_ * D_;
        const int r = t >> 1, c0 = (t & 1) * 64;
        #pragma unroll
        for (int j = 0; j < 64; j += 4) {
            f32x4 v = *(const f32x4*)(w2p + r * D_ + c0 + j);
            #pragma unroll
            for (int q = 0; q < 4; ++q)
                lw2t[(c0 + j + q) * 136 + r] = f2bf(v[q]);
        }
    }
    if (t < 128) {
        const float* w1p = fw1 + f * 4 * D_;
        #pragma unroll
        for (int k = 0; k < 4; ++k) lw1f[t * 8 + k] = w1p[k * D_ + t];
        lw1f[t * 8 + 4] = fb1[f * D_ + t];
    }

    float xa[4], xb[4];
    {
        int na = n0 + wv * 32 + lr;      if (na >= N_) na = N_ - 1;
        int nb = n0 + wv * 32 + lr + 16; if (nb >= N_) nb = N_ - 1;
        long pa = ((long)b * N_ + na) * 3, pb = ((long)b * N_ + nb) * 3;
        xa[0] = pos[pa]; xa[1] = pos[pa + 1]; xa[2] = pos[pa + 2];
        xb[0] = pos[pb]; xb[1] = pos[pb + 1]; xb[2] = pos[pb + 2];
        xa[3] = state[((long)b * N_ + na) * F_ + f];
        xb[3] = state[((long)b * N_ + nb) * F_ + f];
    }
    __syncthreads();

    f32x4 acc[2][8];
    #pragma unroll
    for (int mt = 0; mt < 2; ++mt)
        #pragma unroll
        for (int nt = 0; nt < 8; ++nt) acc[mt][nt] = (f32x4){0.f, 0.f, 0.f, 0.f};

    #pragma unroll
    for (int kb = 0; kb < 4; ++kb) {
        const int e0 = kb * 32 + kg * 8;
        s16x8 ua, ub;
        #pragma unroll
        for (int i = 0; i < 8; ++i) {
            const float* wp = lw1f + (e0 + i) * 8;
            float w0 = wp[0], w1 = wp[1], w2 = wp[2], w3 = wp[3], bb = wp[4];
            ua[i] = (short)f2bf(silu_f(xa[0]*w0 + xa[1]*w1 + xa[2]*w2 + xa[3]*w3 + bb));
            ub[i] = (short)f2bf(silu_f(xb[0]*w0 + xb[1]*w1 + xb[2]*w2 + xb[3]*w3 + bb));
        }
        #pragma unroll
        for (int nt = 0; nt < 8; ++nt) {
            s16x8 bfr = *(const s16x8*)(lw2t + (nt * 16 + lr) * 136 + e0);
            acc[0][nt] = __builtin_amdgcn_mfma_f32_16x16x32_bf16(ua, bfr, acc[0][nt], 0, 0, 0);
            acc[1][nt] = __builtin_amdgcn_mfma_f32_16x16x32_bf16(ub, bfr, acc[1][nt], 0, 0, 0);
        }
    }

    const float* gamma = gb + b * 2 * D_;
    const float* beta  = gamma + D_;
    #pragma unroll
    for (int nt = 0; nt < 8; ++nt) {
        const int col = nt * 16 + lr;
        const float g = gamma[col], be = beta[col];
        const float bs = fb2[f * D_ + col];
        #pragma unroll
        for (int mt = 0; mt < 2; ++mt) {
            const int mbase = wv * 32 + mt * 16 + kg * 4;
            #pragma unroll
            for (int r = 0; r < 4; ++r) {
                const int n = n0 + mbase + r;
                if (n < N_)
                    __builtin_nontemporal_store((acc[mt][nt][r] + bs) * g + be,
                        V + (((long)b * N_ + n) * F_ + f) * D_ + col);
            }
        }
    }
}

// ---------------------------------------------------------------------------
// Edge role: 128 edges, 256 threads. Gather pos, feat folded to 4 inputs,
// bf16 MFMA layer2, nontemporal f32 stores. Self-probes edge dtype.
// ---------------------------------------------------------------------------
static __device__ __forceinline__ void edge_body(
    int sub, int t, unsigned short* lw2t, float* lw1f, int* sx64,
    const float* __restrict__ pos, const int* __restrict__ edges,
    const float* __restrict__ ew1, const float* __restrict__ eb1,
    const float* __restrict__ ew2, const float* __restrict__ eb2,
    float* __restrict__ E)
{
    const int lane = t & 63, wv = t >> 6;
    const int kg = lane >> 4, lr = lane & 15;
    const int e0blk = (sub % EDGE_BX) * 128;
    const int b     = sub / EDGE_BX;

    if (t == 0) {   // int64 edges => every odd int32 word of the first 64 is 0
        int nz = 0;
        for (int j = 0; j < 64; ++j) nz |= edges[2 * j + 1];
        *sx64 = (nz == 0) ? 1 : 0;
    }

    {
        const int r = t >> 1, c0 = (t & 1) * 64;
        #pragma unroll
        for (int j = 0; j < 64; j += 4) {
            f32x4 v = *(const f32x4*)(ew2 + r * D_ + c0 + j);
            #pragma unroll
            for (int q = 0; q < 4; ++q)
                lw2t[(c0 + j + q) * 136 + r] = f2bf(v[q]);
        }
    }
    if (t < 128) {
        #pragma unroll
        for (int k = 0; k < 7; ++k) lw1f[t * 8 + k] = ew1[k * D_ + t];
        lw1f[t * 8 + 7] = eb1[t];
    }
    __syncthreads();   // lw2t, lw1f, sx64 ready

    float xa[4], xb[4];
    {
        const bool x64 = (*sx64 != 0);
        const long ea = (long)b * NE_ + e0blk + wv * 32 + lr;
        const long eb = ea + 16;
        int sa, ra, sb, rb;
        if (x64) {
            sa = edges[ea * 4]; ra = edges[ea * 4 + 2];
            sb = edges[eb * 4]; rb = edges[eb * 4 + 2];
        } else {
            int2 va = *(const int2*)(edges + ea * 2); sa = va.x; ra = va.y;
            int2 vb = *(const int2*)(edges + eb * 2); sb = vb.x; rb = vb.y;
        }
        const float* pp = pos + (long)b * N_ * 3;
        {
            long so = (long)sa * 3, ro = (long)ra * 3;
            xa[0] = pp[ro]     - pp[so];
            xa[1] = pp[ro + 1] - pp[so + 1];
            xa[2] = pp[ro + 2] - pp[so + 2];
            xa[3] = sqrtf(xa[0]*xa[0] + xa[1]*xa[1] + xa[2]*xa[2] + 1e-8f);
        }
        {
            long so = (long)sb * 3, ro = (long)rb * 3;
            xb[0] = pp[ro]     - pp[so];
            xb[1] = pp[ro + 1] - pp[so + 1];
            xb[2] = pp[ro + 2] - pp[so + 2];
            xb[3] = sqrtf(xb[0]*xb[0] + xb[1]*xb[1] + xb[2]*xb[2] + 1e-8f);
        }
    }

    f32x4 acc[2][8];
    #pragma unroll
    for (int mt = 0; mt < 2; ++mt)
        #pragma unroll
        for (int nt = 0; nt < 8; ++nt) acc[mt][nt] = (f32x4){0.f, 0.f, 0.f, 0.f};

    #pragma unroll
    for (int kb = 0; kb < 4; ++kb) {
        const int e0 = kb * 32 + kg * 8;
        s16x8 ua, ub;
        #pragma unroll
        for (int i = 0; i < 8; ++i) {
            const float* wp = lw1f + (e0 + i) * 8;
            float w0 = wp[0] - wp[3];
            float w1 = wp[1] - wp[4];
            float w2 = wp[2] - wp[5];
            float w6 = wp[6];
            float bb = wp[7];
            ua[i] = (short)f2bf(silu_f(xa[0]*w0 + xa[1]*w1 + xa[2]*w2 + xa[3]*w6 + bb));
            ub[i] = (short)f2bf(silu_f(xb[0]*w0 + xb[1]*w1 + xb[2]*w2 + xb[3]*w6 + bb));
        }
        #pragma unroll
        for (int nt = 0; nt < 8; ++nt) {
            s16x8 bfr = *(const s16x8*)(lw2t + (nt * 16 + lr) * 136 + e0);
            acc[0][nt] = __builtin_amdgcn_mfma_f32_16x16x32_bf16(ua, bfr, acc[0][nt], 0, 0, 0);
            acc[1][nt] = __builtin_amdgcn_mfma_f32_16x16x32_bf16(ub, bfr, acc[1][nt], 0, 0, 0);
        }
    }

    #pragma unroll
    for (int nt = 0; nt < 8; ++nt) {
        const int col = nt * 16 + lr;
        const float bs = eb2[col];
        #pragma unroll
        for (int mt = 0; mt < 2; ++mt) {
            const int mbase = wv * 32 + mt * 16 + kg * 4;
            #pragma unroll
            for (int r = 0; r < 4; ++r) {
                const long e = (long)b * NE_ + e0blk + mbase + r;
                __builtin_nontemporal_store(acc[mt][nt][r] + bs, E + e * D_ + col);
            }
        }
    }
}

// ---------------------------------------------------------------------------
// Fused kernel: interleaved node/edge roles (1:4) for co-scheduling.
// ---------------------------------------------------------------------------
__global__ __launch_bounds__(256, 3) void fused_kernel(
    const float* __restrict__ pos, const float* __restrict__ state,
    const int* __restrict__ edges,
    const float* __restrict__ fw1, const float* __restrict__ fb1,
    const float* __restrict__ fw2, const float* __restrict__ fb2,
    const float* __restrict__ ew1, const float* __restrict__ eb1,
    const float* __restrict__ ew2, const float* __restrict__ eb2,
    const float* __restrict__ gb,
    float* __restrict__ V, float* __restrict__ E)
{
    __shared__ __align__(16) unsigned short lw2t[128 * 136];
    __shared__ __align__(16) float lw1f[128 * 8];
    __shared__ int sx64;

    const int bx = blockIdx.x;
    const int t  = threadIdx.x;

    bool isNode; int sub;
    if (bx >= 5 * GROUPS) { isNode = true; sub = GROUPS + (bx - 5 * GROUPS); }
    else {
        int g = bx / 5, s = bx - 5 * g;
        if (s == 0) { isNode = true;  sub = g; }
        else        { isNode = false; sub = g * 4 + (s - 1); }
    }

    if (isNode)
        node_body(sub, t, lw2t, lw1f, pos, state, fw1, fb1, fw2, fb2, gb, V);
    else
        edge_body(sub, t, lw2t, lw1f, &sx64, pos, edges, ew1, eb1, ew2, eb2, E);
}

// ---------------------------------------------------------------------------
extern "C" void kernel_launch(void* const* d_in, const int* in_sizes, int n_in,
                              void* d_out, int out_size, void* d_ws, size_t ws_size,
                              hipStream_t stream)
{
    (void)in_sizes; (void)n_in; (void)out_size; (void)ws_size;

    const float* node_pos  = (const float*)d_in[0];
    const float* state_in  = (const float*)d_in[1];
    const float* time_i    = (const float*)d_in[2];
    const float* conditions= (const float*)d_in[3];
    const float* spatial   = (const float*)d_in[4];
    const int*   edges     = (const int*)d_in[5];
    const float* fields_w1 = (const float*)d_in[6];
    const float* fields_b1 = (const float*)d_in[7];
    const float* fields_w2 = (const float*)d_in[8];
    const float* fields_b2 = (const float*)d_in[9];
    const float* tw1 = (const float*)d_in[10];
    const float* tb1 = (const float*)d_in[11];
    const float* tw2 = (const float*)d_in[12];
    const float* tb2 = (const float*)d_in[13];
    const float* cw1 = (const float*)d_in[14];
    const float* cb1 = (const float*)d_in[15];
    const float* cw2 = (const float*)d_in[16];
    const float* cb2 = (const float*)d_in[17];
    const float* sw1 = (const float*)d_in[18];
    const float* sb1 = (const float*)d_in[19];
    const float* sw2 = (const float*)d_in[20];
    const float* sb2 = (const float*)d_in[21];
    const float* fu_w1 = (const float*)d_in[22];
    const float* fu_b1 = (const float*)d_in[23];
    const float* fu_w2 = (const float*)d_in[24];
    const float* fu_b2 = (const float*)d_in[25];
    const float* fe_w1 = (const float*)d_in[26];
    const float* fe_b1 = (const float*)d_in[27];
    const float* fe_w2 = (const float*)d_in[28];
    const float* fe_b2 = (const float*)d_in[29];

    float* gb = (float*)d_ws;                 // [B][2][D] f32
    float* V  = (float*)d_out;                // [B][N][F][D] f32
    float* E  = V + (long)B_ * N_ * F_ * D_;  // [B][NE][D] f32

    film_kernel<<<dim3(B_), dim3(128), 0, stream>>>(
        time_i, conditions, spatial,
        tw1, tb1, tw2, tb2, cw1, cb1, cw2, cb2, sw1, sb1, sw2, sb2,
        fu_w1, fu_b1, fu_w2, fu_b2, gb);

    fused_kernel<<<dim3(TOTAL_NB), dim3(256), 0, stream>>>(
        node_pos, state_in, edges,
        fields_w1, fields_b1, fields_w2, fields_b2,
        fe_w1, fe_b1, fe_w2, fe_b2, gb, V, E);
}